// Round 8
// baseline (42.085 us; speedup 1.0000x reference)
//
#include <hip/hip_runtime.h>
#include <math.h>

#define B_ 128
#define N_ 16800
#define CHUNK4_ 1050         // uint4 units per chunk (4 chunks per row)
#define NCHUNK 4
#define NBLK (B_ * NCHUNK)   // 512 blocks = 2 per CU
#define NBINS 512            // linear bins over [0,8), width 1/64
#define BINSCALE 64.0f
#define FIXSCALE 1048576.0f  // 2^20 fixed-point for packed bin sums
#define INV_FIX (1.0f / 1048576.0f)
#define FLT_EPS_ 1.1920929e-7f

typedef unsigned long long u64;
typedef unsigned int u32;

__device__ __forceinline__ float bce_of(float x, float y) {
    return fmaxf(x, 0.f) - x * y + __logf(1.f + __expf(-fabsf(x)));
}
__device__ __forceinline__ u32 bin_of(float v) {
    u32 b = (u32)(v * BINSCALE);
    return b > (NBINS - 1u) ? (NBINS - 1u) : b;
}

// Tiny: zero the 128 per-row arrival counters + 1 row-done counter.
__global__ __launch_bounds__(256) void zero_kernel(u32* __restrict__ p) {
    if (threadIdx.x < B_ + 1) p[threadIdx.x] = 0u;
}

// One fused kernel: 512 chunk-blocks stream the data; the last-arriving
// block of each row (leader) merges the row's 4 hists + partials, does the
// exact-binned select, and the last row-leader computes the final B-mean.
__global__ __launch_bounds__(1024) void fused_kernel(
    const float* __restrict__ pbboxs,
    const float* __restrict__ plabels,
    const float* __restrict__ gbboxs,
    const float* __restrict__ glabels,
    const float* __restrict__ ancs,
    u64*   __restrict__ g_h,      // [NBLK][NBINS] packed (sum<<24 | count)
    float* __restrict__ g_lb,     // [NBLK]
    float* __restrict__ g_pbce,   // [NBLK]
    int*   __restrict__ g_pn,     // [NBLK]
    u32*   __restrict__ g_ctr,    // [B_+1]: per-row counters + done counter
    float* __restrict__ g_rowc,   // [3][B_]
    float* __restrict__ out)
{
    __shared__ u64 s_h[NBINS];        // 4 KB
    __shared__ float s_rf[16], s_rf2[16];
    __shared__ int   s_ri[16];
    __shared__ float s_pp[8];         // leader: lb[0..3], pbce[0..3]
    __shared__ int   s_pni[4];
    __shared__ u32   s_wt[8];
    __shared__ u32   s_sel[2];
    __shared__ float s_tavg;
    __shared__ int   s_lead, s_last, s_k;

    const int tid  = threadIdx.x;
    const int lane = tid & 63;
    const int wave = tid >> 6;
    const int b    = blockIdx.x >> 2;
    const int h    = blockIdx.x & 3;

    if (tid < NBINS) s_h[tid] = 0ull;
    __syncthreads();

    const uint4*  pl4 = (const uint4*)(plabels + (size_t)b * N_) + h * CHUNK4_;
    const uint4*  gl4 = (const uint4*)(glabels + (size_t)b * N_) + h * CHUNK4_;
    const float4* p4  = (const float4*)(pbboxs + (size_t)b * N_ * 4);
    const float4* g4  = (const float4*)(gbboxs + (size_t)b * N_ * 4);
    const float4* a4  = (const float4*)ancs;

    float acc_lb = 0.f, acc_pbce = 0.f;
    int   acc_pn = 0;

    // ---- dense streaming + inline sparse positives (single load burst) ----
    for (int i = tid; i < CHUNK4_; i += 1024) {
        uint4 xu = pl4[i];
        uint4 yu = gl4[i];
        unsigned int xb[4] = {xu.x, xu.y, xu.z, xu.w};
        unsigned int yb[4] = {yu.x, yu.y, yu.z, yu.w};
        #pragma unroll
        for (int j = 0; j < 4; ++j) {
            float x = __uint_as_float(xb[j]);
            float y = __uint_as_float(yb[j]);
            float bce = bce_of(x, y);
            bool  pos = (y > 0.f);
            float lneg = pos ? 0.f : bce;
            u64 pk = ((u64)(u32)(lneg * FIXSCALE) << 24) | 1ull;
            atomicAdd(&s_h[bin_of(lneg)], pk);
            if (pos) {
                acc_pbce += bce;
                acc_pn   += 1;
                int n = (h * CHUNK4_ + i) * 4 + j;
                float4 p = p4[n], g = g4[n], a = a4[n];
                float d0 = p.x - 10.f * __fdividef(g.x - a.x, a.z);
                float d1 = p.y - 10.f * __fdividef(g.y - a.y, a.w);
                float d2 = p.z - 5.f * __logf(__fdividef(g.z, a.z));
                float d3 = p.w - 5.f * __logf(__fdividef(g.w, a.w));
                float a0 = fabsf(d0), a1 = fabsf(d1), a2 = fabsf(d2), a3 = fabsf(d3);
                acc_lb += ((a0 < 1.f) ? 0.5f * d0 * d0 : a0 - 0.5f)
                        + ((a1 < 1.f) ? 0.5f * d1 * d1 : a1 - 0.5f)
                        + ((a2 < 1.f) ? 0.5f * d2 * d2 : a2 - 0.5f)
                        + ((a3 < 1.f) ? 0.5f * d3 * d3 : a3 - 0.5f);
            }
        }
    }
    __syncthreads();

    // chunk hist write-out: 512 u64 = 256 uint4, coalesced
    if (tid < NBINS / 2)
        ((uint4*)(g_h + (size_t)blockIdx.x * NBINS))[tid] = ((const uint4*)s_h)[tid];

    // chunk partial reduce
    #pragma unroll
    for (int off = 32; off > 0; off >>= 1) {
        acc_lb   += __shfl_xor(acc_lb, off);
        acc_pbce += __shfl_xor(acc_pbce, off);
        acc_pn   += __shfl_xor(acc_pn, off);
    }
    if (lane == 0) { s_rf[wave] = acc_lb; s_rf2[wave] = acc_pbce; s_ri[wave] = acc_pn; }
    __syncthreads();
    if (tid == 0) {
        float t1 = 0.f, t2 = 0.f; int t3 = 0;
        for (int w = 0; w < 16; ++w) { t1 += s_rf[w]; t2 += s_rf2[w]; t3 += s_ri[w]; }
        g_lb[blockIdx.x] = t1; g_pbce[blockIdx.x] = t2; g_pn[blockIdx.x] = t3;
    }
    __syncthreads();   // all threads' global stores issued before election

    // ---- row-leader election: 4th arriver runs the select ----
    if (tid == 0) {
        __threadfence();
        u32 old = atomicAdd(&g_ctr[b], 1u);
        s_lead = (old == NCHUNK - 1) ? 1 : 0;
    }
    __syncthreads();
    if (!s_lead) return;

    // ---- leader: merge partials + hists (atomic reads = coherent) ----
    if (tid < 4)        s_pp[tid]      = atomicAdd(&g_lb[4 * b + tid], 0.f);
    else if (tid < 8)   s_pp[tid]      = atomicAdd(&g_pbce[4 * b + tid - 4], 0.f);
    else if (tid < 12)  s_pni[tid - 8] = atomicAdd(&g_pn[4 * b + tid - 8], 0);
    if (tid < NBINS) s_h[tid] = 0ull;
    __syncthreads();
    {
        const int ch0 = (tid >> 9) * 2;          // threads<512: chunks 0,1; else 2,3
        const int bin = tid & (NBINS - 1);
        u64 v = atomicAdd(&g_h[(size_t)(4 * b + ch0) * NBINS + bin], 0ull)
              + atomicAdd(&g_h[(size_t)(4 * b + ch0 + 1) * NBINS + bin], 0ull);
        atomicAdd(&s_h[bin], v);
    }
    if (tid == 0) {
        int pn = s_pni[0] + s_pni[1] + s_pni[2] + s_pni[3];
        int k = 3 * pn; if (k > N_) k = N_;
        s_k = k;
    }
    __syncthreads();
    const int k = s_k;

    float sum_sel = 0.f;   // meaningful on tid 0
    if (k > 0) {
        u32 c = 0u; float sv = 0.f; u32 suf = 0u;
        if (tid < NBINS) {
            u64 hh = s_h[tid];
            c  = (u32)(hh & 0xFFFFFFull);
            sv = (float)(hh >> 24) * INV_FIX;
            suf = c;
        }
        // inclusive suffix scan over bins (waves 0..7 hold tid<512)
        #pragma unroll
        for (int off = 1; off < 64; off <<= 1) {
            u32 o = __shfl_down(suf, off);
            if (lane + off < 64) suf += o;
        }
        if (tid < NBINS && lane == 0) s_wt[wave] = suf;
        __syncthreads();
        if (tid < NBINS) {
            u32 above = 0u;
            for (int w = wave + 1; w < 8; ++w) above += s_wt[w];
            u32 r  = suf + above;   // suffix count from bin tid
            u32 r2 = r - c;
            if (r >= (u32)k && r2 < (u32)k) {   // exactly one bin fires; c >= 1
                s_sel[0] = (u32)tid;
                s_sel[1] = (u32)k - r2;
                s_tavg   = sv / (float)c;
            }
        }
        __syncthreads();
        const u32 b1 = s_sel[0], remk = s_sel[1];
        float sg = (tid < NBINS && (u32)tid > b1) ? sv : 0.f;
        #pragma unroll
        for (int off = 32; off > 0; off >>= 1) sg += __shfl_xor(sg, off);
        if (lane == 0) s_rf[wave] = sg;
        __syncthreads();
        if (tid == 0) {
            float t = 0.f;
            for (int w = 0; w < 16; ++w) t += s_rf[w];
            sum_sel = t + (float)remk * s_tavg;
        }
    }

    // ---- per-row contribution + last-row final mean ----
    if (tid == 0) {
        int   pn     = s_pni[0] + s_pni[1] + s_pni[2] + s_pni[3];
        float row_lb = s_pp[0] + s_pp[1] + s_pp[2] + s_pp[3];
        float row_pb = s_pp[4] + s_pp[5] + s_pp[6] + s_pp[7];
        float nm  = (pn > 0) ? 1.f : 0.f;
        float pcn = fmaxf((float)pn, FLT_EPS_);
        g_rowc[b]          = row_lb * nm / pcn;
        g_rowc[B_ + b]     = (row_pb + sum_sel) * nm / pcn;
        g_rowc[2 * B_ + b] = nm / pcn;
        __threadfence();
        u32 old = atomicAdd(&g_ctr[B_], 1u);
        s_last = (old == (u32)(B_ - 1)) ? 1 : 0;
    }
    __syncthreads();
    if (s_last && wave == 0) {
        // atomic reads bypass stale cache lines; fixed tree -> deterministic
        float lb_t = atomicAdd(&g_rowc[lane], 0.f)          + atomicAdd(&g_rowc[lane + 64], 0.f);
        float ll_t = atomicAdd(&g_rowc[B_ + lane], 0.f)     + atomicAdd(&g_rowc[B_ + lane + 64], 0.f);
        float w_t  = atomicAdd(&g_rowc[2 * B_ + lane], 0.f) + atomicAdd(&g_rowc[2 * B_ + lane + 64], 0.f);
        #pragma unroll
        for (int off = 32; off > 0; off >>= 1) {
            lb_t += __shfl_xor(lb_t, off);
            ll_t += __shfl_xor(ll_t, off);
            w_t  += __shfl_xor(w_t, off);
        }
        if (lane == 0) {
            float LB = lb_t * (1.f / B_);
            float LL = ll_t * (1.f / B_);
            float W  = w_t  * (1.f / B_);
            out[0] = (LB + LL) * W;
            out[1] = LB;
            out[2] = LL;
        }
    }
}

extern "C" void kernel_launch(void* const* d_in, const int* in_sizes, int n_in,
                              void* d_out, int out_size, void* d_ws, size_t ws_size,
                              hipStream_t stream) {
    const float* pbboxs  = (const float*)d_in[0];
    const float* plabels = (const float*)d_in[1];
    const float* gbboxs  = (const float*)d_in[2];
    const float* glabels = (const float*)d_in[3];
    const float* ancs    = (const float*)d_in[4];
    float* out = (float*)d_out;

    char* ws = (char*)d_ws;
    u32* g_ctr = (u32*)ws;                 // 129 u32 = 516 B -> reserve 1024 B
    u64* g_h   = (u64*)(ws + 1024);        // 2 MB  (R7 BUG: was +512, g_ctr[128] aliased g_h[0])
    size_t off = 1024 + (size_t)NBLK * NBINS * 8;
    float* g_lb   = (float*)(ws + off);  off += NBLK * 4;
    float* g_pbce = (float*)(ws + off);  off += NBLK * 4;
    int*   g_pn   = (int*)(ws + off);    off += NBLK * 4;
    float* g_rowc = (float*)(ws + off);

    zero_kernel<<<1, 256, 0, stream>>>(g_ctr);
    fused_kernel<<<NBLK, 1024, 0, stream>>>(
        pbboxs, plabels, gbboxs, glabels, ancs,
        g_h, g_lb, g_pbce, g_pn, g_ctr, g_rowc, out);
}

// Round 9
// 23.741 us; speedup vs baseline: 1.7727x; 1.7727x over previous
//
#include <hip/hip_runtime.h>
#include <math.h>

#define B_ 128
#define N_ 16800
#define CHUNK4_ 1050         // uint4 units per chunk (4 chunks per row)
#define NCHUNK 4
#define NBLK (B_ * NCHUNK)   // 512 blocks = 2 per CU
#define NBINS 512            // linear bins over [0,8), width 1/64 (absmax 0.0 proven R8)
#define BINSCALE 64.0f
#define FIXSCALE 1048576.0f  // 2^20 fixed-point for packed bin sums
#define INV_FIX (1.0f / 1048576.0f)
#define FLT_EPS_ 1.1920929e-7f

typedef unsigned long long u64;
typedef unsigned int u32;

__device__ __forceinline__ float bce_of(float x, float y) {
    return fmaxf(x, 0.f) - x * y + __logf(1.f + __expf(-fabsf(x)));
}
__device__ __forceinline__ u32 bin_of(float v) {
    u32 b = (u32)(v * BINSCALE);
    return b > (NBINS - 1u) ? (NBINS - 1u) : b;
}

// ---------- Kernel A: streaming pass, 512 blocks, packed-u64 LDS hist ----------
__global__ __launch_bounds__(1024) void pass1_kernel(
    const float* __restrict__ pbboxs,
    const float* __restrict__ plabels,
    const float* __restrict__ gbboxs,
    const float* __restrict__ glabels,
    const float* __restrict__ ancs,
    u64*   __restrict__ g_h,      // [NBLK][NBINS] packed (sum<<24 | count)
    float* __restrict__ g_lb,     // [NBLK]
    float* __restrict__ g_pbce,   // [NBLK]
    int*   __restrict__ g_pn,     // [NBLK]
    u32*   __restrict__ g_cnt)    // arrival counter for kernel B (zeroed here)
{
    __shared__ u64 s_h[NBINS];    // 4 KB
    __shared__ float s_rf[16], s_rf2[16];
    __shared__ int   s_ri[16];

    const int tid  = threadIdx.x;
    const int lane = tid & 63;
    const int wave = tid >> 6;
    const int b    = blockIdx.x >> 2;
    const int h    = blockIdx.x & 3;

    if (tid < NBINS) s_h[tid] = 0ull;
    if (blockIdx.x == 0 && tid == 0) *g_cnt = 0u;   // visible to kernel B via stream order
    __syncthreads();

    const uint4*  pl4 = (const uint4*)(plabels + (size_t)b * N_) + h * CHUNK4_;
    const uint4*  gl4 = (const uint4*)(glabels + (size_t)b * N_) + h * CHUNK4_;
    const float4* p4  = (const float4*)(pbboxs + (size_t)b * N_ * 4);
    const float4* g4  = (const float4*)(gbboxs + (size_t)b * N_ * 4);
    const float4* a4  = (const float4*)ancs;

    float acc_lb = 0.f, acc_pbce = 0.f;
    int   acc_pn = 0;

    // dense streaming + inline sparse positives (single load burst)
    for (int i = tid; i < CHUNK4_; i += 1024) {
        uint4 xu = pl4[i];
        uint4 yu = gl4[i];
        unsigned int xb[4] = {xu.x, xu.y, xu.z, xu.w};
        unsigned int yb[4] = {yu.x, yu.y, yu.z, yu.w};
        #pragma unroll
        for (int j = 0; j < 4; ++j) {
            float x = __uint_as_float(xb[j]);
            float y = __uint_as_float(yb[j]);
            float bce = bce_of(x, y);
            bool  pos = (y > 0.f);
            float lneg = pos ? 0.f : bce;
            u64 pk = ((u64)(u32)(lneg * FIXSCALE) << 24) | 1ull;
            atomicAdd(&s_h[bin_of(lneg)], pk);
            if (pos) {
                acc_pbce += bce;
                acc_pn   += 1;
                int n = (h * CHUNK4_ + i) * 4 + j;
                float4 p = p4[n], g = g4[n], a = a4[n];
                float d0 = p.x - 10.f * __fdividef(g.x - a.x, a.z);
                float d1 = p.y - 10.f * __fdividef(g.y - a.y, a.w);
                float d2 = p.z - 5.f * __logf(__fdividef(g.z, a.z));
                float d3 = p.w - 5.f * __logf(__fdividef(g.w, a.w));
                float a0 = fabsf(d0), a1 = fabsf(d1), a2 = fabsf(d2), a3 = fabsf(d3);
                acc_lb += ((a0 < 1.f) ? 0.5f * d0 * d0 : a0 - 0.5f)
                        + ((a1 < 1.f) ? 0.5f * d1 * d1 : a1 - 0.5f)
                        + ((a2 < 1.f) ? 0.5f * d2 * d2 : a2 - 0.5f)
                        + ((a3 < 1.f) ? 0.5f * d3 * d3 : a3 - 0.5f);
            }
        }
    }
    __syncthreads();

    // hist write-out: 512 u64 = 256 uint4, coalesced plain stores
    if (tid < NBINS / 2)
        ((uint4*)(g_h + (size_t)blockIdx.x * NBINS))[tid] = ((const uint4*)s_h)[tid];

    #pragma unroll
    for (int off = 32; off > 0; off >>= 1) {
        acc_lb   += __shfl_xor(acc_lb, off);
        acc_pbce += __shfl_xor(acc_pbce, off);
        acc_pn   += __shfl_xor(acc_pn, off);
    }
    if (lane == 0) { s_rf[wave] = acc_lb; s_rf2[wave] = acc_pbce; s_ri[wave] = acc_pn; }
    __syncthreads();
    if (tid == 0) {
        float t1 = 0.f, t2 = 0.f; int t3 = 0;
        for (int w = 0; w < 16; ++w) { t1 += s_rf[w]; t2 += s_rf2[w]; t3 += s_ri[w]; }
        g_lb[blockIdx.x] = t1; g_pbce[blockIdx.x] = t2; g_pn[blockIdx.x] = t3;
    }
}

// ---------- Kernel B: per-row select (plain loads) + fused final mean ----------
__global__ __launch_bounds__(1024) void select_final_kernel(
    const u64*   __restrict__ g_h,
    const float* __restrict__ g_lb,
    const float* __restrict__ g_pbce,
    const int*   __restrict__ g_pn,
    float* __restrict__ g_rowc,   // [3][B_]
    u32*   __restrict__ g_cnt,    // zeroed by pass1
    float* __restrict__ out)
{
    __shared__ u32   s_wt[8];
    __shared__ float s_rf[16];
    __shared__ u32   s_sel[2];
    __shared__ float s_tavg;
    __shared__ int   s_last;

    const int tid  = threadIdx.x;
    const int lane = tid & 63;
    const int wave = tid >> 6;
    const int b    = blockIdx.x;

    const int pn = g_pn[4*b] + g_pn[4*b+1] + g_pn[4*b+2] + g_pn[4*b+3];
    int k = 3 * pn; if (k > N_) k = N_;

    float sum_sel = 0.f;   // meaningful on tid 0

    if (k > 0) {           // block-uniform branch
        // thread t < 512 owns bin t; merge 4 chunk hists with plain coalesced
        // loads (kernel boundary guarantees coherence). Packed adds safe:
        // total count 16800 < 2^24, no carry into sum field.
        u32 c = 0u; float sv = 0.f; u32 suf = 0u;
        if (tid < NBINS) {
            u64 hh = g_h[(size_t)(4 * b + 0) * NBINS + tid]
                   + g_h[(size_t)(4 * b + 1) * NBINS + tid]
                   + g_h[(size_t)(4 * b + 2) * NBINS + tid]
                   + g_h[(size_t)(4 * b + 3) * NBINS + tid];
            c  = (u32)(hh & 0xFFFFFFull);
            sv = (float)(hh >> 24) * INV_FIX;
            suf = c;
        }
        // inclusive suffix scan over bins (waves 0..7 hold tid<512)
        #pragma unroll
        for (int off = 1; off < 64; off <<= 1) {
            u32 o = __shfl_down(suf, off);
            if (lane + off < 64) suf += o;
        }
        if (tid < NBINS && lane == 0) s_wt[wave] = suf;
        __syncthreads();
        if (tid < NBINS) {
            u32 above = 0u;
            for (int w = wave + 1; w < 8; ++w) above += s_wt[w];
            u32 r  = suf + above;   // inclusive suffix count from bin tid
            u32 r2 = r - c;
            if (r >= (u32)k && r2 < (u32)k) {   // exactly one bin fires; c >= 1
                s_sel[0] = (u32)tid;
                s_sel[1] = (u32)k - r2;
                s_tavg   = sv / (float)c;
            }
        }
        __syncthreads();
        const u32 b1 = s_sel[0], remk = s_sel[1];
        float sg = (tid < NBINS && (u32)tid > b1) ? sv : 0.f;
        #pragma unroll
        for (int off = 32; off > 0; off >>= 1) sg += __shfl_xor(sg, off);
        if (lane == 0) s_rf[wave] = sg;
        __syncthreads();
        if (tid == 0) {
            float t = 0.f;
            for (int w = 0; w < 16; ++w) t += s_rf[w];
            sum_sel = t + (float)remk * s_tavg;
        }
    }

    // ---- per-row contribution + last-block final mean ----
    if (tid == 0) {
        float row_lb = g_lb[4*b] + g_lb[4*b+1] + g_lb[4*b+2] + g_lb[4*b+3];
        float row_pb = g_pbce[4*b] + g_pbce[4*b+1] + g_pbce[4*b+2] + g_pbce[4*b+3];
        float nm  = (pn > 0) ? 1.f : 0.f;
        float pcn = fmaxf((float)pn, FLT_EPS_);
        g_rowc[b]          = row_lb * nm / pcn;
        g_rowc[B_ + b]     = (row_pb + sum_sel) * nm / pcn;
        g_rowc[2 * B_ + b] = nm / pcn;
        __threadfence();
        u32 old = atomicAdd(g_cnt, 1u);
        s_last = (old == (u32)(B_ - 1)) ? 1 : 0;
    }
    __syncthreads();
    if (s_last && wave == 0) {
        // atomic reads bypass stale cache lines; fixed tree -> deterministic
        float lb_t = atomicAdd(&g_rowc[lane], 0.f)          + atomicAdd(&g_rowc[lane + 64], 0.f);
        float ll_t = atomicAdd(&g_rowc[B_ + lane], 0.f)     + atomicAdd(&g_rowc[B_ + lane + 64], 0.f);
        float w_t  = atomicAdd(&g_rowc[2 * B_ + lane], 0.f) + atomicAdd(&g_rowc[2 * B_ + lane + 64], 0.f);
        #pragma unroll
        for (int off = 32; off > 0; off >>= 1) {
            lb_t += __shfl_xor(lb_t, off);
            ll_t += __shfl_xor(ll_t, off);
            w_t  += __shfl_xor(w_t, off);
        }
        if (lane == 0) {
            float LB = lb_t * (1.f / B_);
            float LL = ll_t * (1.f / B_);
            float W  = w_t  * (1.f / B_);
            out[0] = (LB + LL) * W;
            out[1] = LB;
            out[2] = LL;
        }
    }
}

extern "C" void kernel_launch(void* const* d_in, const int* in_sizes, int n_in,
                              void* d_out, int out_size, void* d_ws, size_t ws_size,
                              hipStream_t stream) {
    const float* pbboxs  = (const float*)d_in[0];
    const float* plabels = (const float*)d_in[1];
    const float* gbboxs  = (const float*)d_in[2];
    const float* glabels = (const float*)d_in[3];
    const float* ancs    = (const float*)d_in[4];
    float* out = (float*)d_out;

    char* ws = (char*)d_ws;
    u32* g_cnt = (u32*)ws;                 // 4 B, pad to 1024
    u64* g_h   = (u64*)(ws + 1024);        // 512*512*8 = 2.1 MB
    size_t off = 1024 + (size_t)NBLK * NBINS * 8;
    float* g_lb   = (float*)(ws + off);  off += NBLK * 4;
    float* g_pbce = (float*)(ws + off);  off += NBLK * 4;
    int*   g_pn   = (int*)(ws + off);    off += NBLK * 4;
    float* g_rowc = (float*)(ws + off);

    // no memset: pass1 zeroes g_cnt; every other ws word written before read
    pass1_kernel<<<NBLK, 1024, 0, stream>>>(
        pbboxs, plabels, gbboxs, glabels, ancs, g_h, g_lb, g_pbce, g_pn, g_cnt);
    select_final_kernel<<<B_, 1024, 0, stream>>>(
        g_h, g_lb, g_pbce, g_pn, g_rowc, g_cnt, out);
}